// Round 1
// baseline (12094.958 us; speedup 1.0000x reference)
//
#include <hip/hip_runtime.h>
#include <hip/hip_bf16.h>

#define DEV __device__ __forceinline__

typedef _Float16 f16;
typedef _Float16 f16x8 __attribute__((ext_vector_type(8)));
typedef _Float16 f16x4 __attribute__((ext_vector_type(4)));
typedef float    f32x4 __attribute__((ext_vector_type(4)));

constexpr int Bsz = 4096;   // batch
constexpr int DZ  = 512;
constexpr int DIM = 63;
constexpr int T   = 120;
constexpr int H   = 1024;
constexpr int G4  = 4096;   // 4*H
constexpr int KC  = 1088;   // H + 64 (pose padded to 64)

DEV void gload16(f16* lds, const f16* g) {
  __builtin_amdgcn_global_load_lds(
      (const __attribute__((address_space(1))) unsigned int*)g,
      (__attribute__((address_space(3))) unsigned int*)lds, 16, 0, 0);
}

DEV float sigf(float x) { return 1.f / (1.f + __expf(-x)); }
DEV float tanh_fast(float x) { float e = __expf(2.f * x); return (e - 1.f) / (e + 1.f); }

enum { EPI_RELU_F16 = 0, EPI_F16 = 1, EPI_GATESX = 2, EPI_LSTM = 3, EPI_POSE = 4 };

struct GArgs {
  const f16* A;  int ldA;
  const f16* Bm; int ldB;
  int K;
  const float* bias;
  f16* O; int ldO;
  // lstm epilogue
  const f16* gx; float* c32; f16* inp;
  // pose epilogue
  float* outp; int t;
};

// A[M,K] row-major f16, B[N,K] row-major f16 (i.e. B^T), C = A*B^T, f32 accum.
// m97 structure: single-buffered LDS, global_load_lds width 16, 2 barriers / K-step.
template <int BM, int BN, int WM, int WN, int EPI>
__global__ __launch_bounds__((BM / WM) * (BN / WN) * 64)
void gemm_k(GArgs p) {
  constexpr int WN_CNT = BN / WN;
  constexpr int NW = (BM / WM) * WN_CNT;
  constexpr int NT = NW * 64;
  constexpr int MF = WM / 16, NF = WN / 16;
  constexpr int AIT = BM * 8 / NT, BIT = BN * 8 / NT;
  constexpr int RPI = NT / 8;  // staging rows per iter

  __shared__ __align__(16) f16 sA[BM * 64];
  __shared__ __align__(16) f16 sB[BN * 64];

  const int tid = threadIdx.x, lane = tid & 63;
  const int wv = tid >> 6, wm = wv / WN_CNT, wn = wv % WN_CNT;
  const int bm = blockIdx.x, bn = blockIdx.y;

  f32x4 acc[MF][NF] = {};

  const int sr = tid >> 3;          // 0..31 (NT==256 in all instantiations)
  const int sc = (tid & 7) * 8;
  const f16* gA = p.A + (size_t)(bm * BM + sr) * p.ldA + sc;
  const f16* gB;
  if constexpr (EPI == EPI_LSTM) {
    // gate-major gather: staging iter `it` covers gate `it`; B rows = it*1024 + bn*32 + sr
    gB = p.Bm + (size_t)(bn * 32 + sr) * p.ldB + sc;
  } else {
    gB = p.Bm + (size_t)(bn * BN + sr) * p.ldB + sc;
  }
  f16* lA = sA + tid * 8;
  f16* lB = sB + tid * 8;

  for (int k0 = 0; k0 < p.K; k0 += 64) {
#pragma unroll
    for (int it = 0; it < AIT; ++it)
      gload16(lA + it * NT * 8, gA + (size_t)it * RPI * p.ldA + k0);
#pragma unroll
    for (int it = 0; it < BIT; ++it) {
      if constexpr (EPI == EPI_LSTM)
        gload16(lB + it * NT * 8, gB + (size_t)it * 1024 * p.ldB + k0);
      else
        gload16(lB + it * NT * 8, gB + (size_t)it * RPI * p.ldB + k0);
    }
    __syncthreads();
#pragma unroll
    for (int kk = 0; kk < 2; ++kk) {
      f16x8 af[MF], bf[NF];
#pragma unroll
      for (int i = 0; i < MF; ++i)
        af[i] = *(const f16x8*)(sA + (wm * WM + i * 16 + (lane & 15)) * 64 + kk * 32 + (lane >> 4) * 8);
#pragma unroll
      for (int j = 0; j < NF; ++j)
        bf[j] = *(const f16x8*)(sB + (wn * WN + j * 16 + (lane & 15)) * 64 + kk * 32 + (lane >> 4) * 8);
#pragma unroll
      for (int i = 0; i < MF; ++i)
#pragma unroll
        for (int j = 0; j < NF; ++j)
          acc[i][j] = __builtin_amdgcn_mfma_f32_16x16x32_f16(af[i], bf[j], acc[i][j], 0, 0, 0);
    }
    __syncthreads();
  }

  const int r0 = bm * BM + wm * WM;
  const int c0 = bn * BN + wn * WN;

  if constexpr (EPI == EPI_LSTM) {
    // WN==128, wn==0. acc[i][0..1]=i-gate, [2..3]=f, [4..5]=g, [6..7]=o
#pragma unroll
    for (int i = 0; i < MF; ++i) {
#pragma unroll
      for (int jj = 0; jj < 2; ++jj) {
        const int jl = jj * 16 + (lane & 15);
        const int jg = bn * 32 + jl;
#pragma unroll
        for (int r = 0; r < 4; ++r) {
          const int row = r0 + i * 16 + ((lane >> 4) << 2) + r;
          f16x4 g4v = *(const f16x4*)(p.gx + (size_t)row * G4 + jg * 4);
          float ig = acc[i][0 + jj][r] + (float)g4v[0];
          float fg = acc[i][2 + jj][r] + (float)g4v[1];
          float gg = acc[i][4 + jj][r] + (float)g4v[2];
          float og = acc[i][6 + jj][r] + (float)g4v[3];
          float c = p.c32[(size_t)row * H + jg];
          c = sigf(fg) * c + sigf(ig) * tanh_fast(gg);
          float h = sigf(og) * tanh_fast(c);
          p.c32[(size_t)row * H + jg] = c;
          p.inp[(size_t)row * KC + jg] = (f16)h;
        }
      }
    }
  } else if constexpr (EPI == EPI_POSE) {
#pragma unroll
    for (int i = 0; i < MF; ++i)
#pragma unroll
      for (int j = 0; j < NF; ++j)
#pragma unroll
        for (int r = 0; r < 4; ++r) {
          const int row = r0 + i * 16 + ((lane >> 4) << 2) + r;
          const int col = c0 + j * 16 + (lane & 15);
          float v = acc[i][j][r] + p.bias[col];
          p.inp[(size_t)row * KC + H + col] = (f16)v;   // feedback (col 63 == 0 pad)
          if (col < DIM)
            p.outp[(size_t)row * (T * DIM) + (size_t)p.t * DIM + col] = v;
        }
  } else {
#pragma unroll
    for (int i = 0; i < MF; ++i)
#pragma unroll
      for (int j = 0; j < NF; ++j)
#pragma unroll
        for (int r = 0; r < 4; ++r) {
          const int row = r0 + i * 16 + ((lane >> 4) << 2) + r;
          const int col = c0 + j * 16 + (lane & 15);
          float v = acc[i][j][r] + p.bias[col];
          if constexpr (EPI == EPI_RELU_F16) v = fmaxf(v, 0.f);
          if constexpr (EPI == EPI_GATESX)
            p.O[(size_t)row * G4 + ((size_t)(col & 1023) << 2) + (col >> 10)] = (f16)v;
          else
            p.O[(size_t)row * p.ldO + col] = (f16)v;
        }
  }
}

// ---------------- prologue helper kernels ----------------
__global__ void k_cvt(const float* s, f16* d, int n) {
  for (int i = blockIdx.x * blockDim.x + threadIdx.x; i < n; i += gridDim.x * blockDim.x)
    d[i] = (f16)s[i];
}
__global__ void k_pad_rows(const float* s, f16* d, int rows, int n) {  // cols = 512
  for (int i = blockIdx.x * blockDim.x + threadIdx.x; i < n; i += gridDim.x * blockDim.x) {
    int r = i >> 9;
    d[i] = (r < rows) ? (f16)s[i] : (f16)0.f;
  }
}
__global__ void k_pack_wihx(const float* W, f16* d) {  // W_ih[4096,575] -> [4096,512]
  for (int i = blockIdx.x * blockDim.x + threadIdx.x; i < G4 * DZ; i += gridDim.x * blockDim.x) {
    int n = i >> 9, k = i & 511;
    d[i] = (f16)W[n * 575 + k];
  }
}
__global__ void k_pack_wcat(const float* Wih, const float* Whh, f16* d) {  // [4096,1088]
  for (int i = blockIdx.x * blockDim.x + threadIdx.x; i < G4 * KC; i += gridDim.x * blockDim.x) {
    int n = i / KC, k = i - n * KC;
    float v = (k < H) ? Whh[n * H + k] : ((k < H + DIM) ? Wih[n * 575 + DZ + (k - H)] : 0.f);
    d[i] = (f16)v;
  }
}
__global__ void k_bias(const float* bih, const float* bhh, float* bsum,
                       const float* bp2, float* bp2p, const float* b2, float* b2p) {
  int i = blockIdx.x * blockDim.x + threadIdx.x;
  if (i < G4) bsum[i] = bih[i] + bhh[i];
  if (i < 64) {
    bp2p[i] = (i < DIM) ? bp2[i] : 0.f;
    b2p[i]  = (i < DIM) ? b2[i]  : 0.f;
  }
}
__global__ void k_init(float* c32, f16* inp) {  // zero c and h-region of inpA
  for (int i = blockIdx.x * blockDim.x + threadIdx.x; i < Bsz * H; i += gridDim.x * blockDim.x) {
    c32[i] = 0.f;
    inp[(size_t)(i >> 10) * KC + (i & 1023)] = (f16)0.f;
  }
}

extern "C" void kernel_launch(void* const* d_in, const int* in_sizes, int n_in,
                              void* d_out, int out_size, void* d_ws, size_t ws_size,
                              hipStream_t stream) {
  const float* x_in = (const float*)d_in[0];
  const float* Wlin = (const float*)d_in[1];
  const float* blin = (const float*)d_in[2];
  const float* Wp1  = (const float*)d_in[3];
  const float* bp1  = (const float*)d_in[4];
  const float* Wp2  = (const float*)d_in[5];
  const float* bp2  = (const float*)d_in[6];
  const float* Wih  = (const float*)d_in[7];
  const float* bih  = (const float*)d_in[8];
  const float* Whh  = (const float*)d_in[9];
  const float* bhh  = (const float*)d_in[10];
  const float* W1   = (const float*)d_in[11];
  const float* b1   = (const float*)d_in[12];
  const float* W2   = (const float*)d_in[13];
  const float* b2   = (const float*)d_in[14];
  float* out = (float*)d_out;

  char* w = (char*)d_ws;
  auto alloc = [&](size_t bytes) { char* r = w; w += (bytes + 255) & ~(size_t)255; return r; };
  f16*   inpA   = (f16*)alloc((size_t)Bsz * KC * 2);
  f16*   inpB   = (f16*)alloc((size_t)Bsz * KC * 2);
  float* c32    = (float*)alloc((size_t)Bsz * H * 4);
  f16*   gx16   = (f16*)alloc((size_t)Bsz * G4 * 2);
  f16*   wcat   = (f16*)alloc((size_t)G4 * KC * 2);
  f16*   wihx   = (f16*)alloc((size_t)G4 * DZ * 2);
  f16*   wlin16 = (f16*)alloc((size_t)DZ * DZ * 2);
  f16*   wp1_16 = (f16*)alloc((size_t)DZ * DZ * 2);
  f16*   wp2p   = (f16*)alloc((size_t)64 * DZ * 2);
  f16*   w1_16  = (f16*)alloc((size_t)DZ * H * 2);
  f16*   w2p    = (f16*)alloc((size_t)64 * DZ * 2);
  f16*   xin16  = (f16*)alloc((size_t)Bsz * DZ * 2);
  f16*   x16    = (f16*)alloc((size_t)Bsz * DZ * 2);
  f16*   t16    = (f16*)alloc((size_t)Bsz * DZ * 2);
  float* bsum   = (float*)alloc((size_t)G4 * 4);
  float* bp2p_  = (float*)alloc(64 * 4);
  float* b2p    = (float*)alloc(64 * 4);

  dim3 blk(256);
  auto g1 = [](int n) { int b = (n + 255) / 256; return dim3(b > 2048 ? 2048 : b); };

  k_cvt<<<g1(Bsz * DZ), blk, 0, stream>>>(x_in, xin16, Bsz * DZ);
  k_cvt<<<g1(DZ * DZ), blk, 0, stream>>>(Wlin, wlin16, DZ * DZ);
  k_cvt<<<g1(DZ * DZ), blk, 0, stream>>>(Wp1, wp1_16, DZ * DZ);
  k_cvt<<<g1(DZ * H), blk, 0, stream>>>(W1, w1_16, DZ * H);
  k_pad_rows<<<g1(64 * DZ), blk, 0, stream>>>(Wp2, wp2p, DIM, 64 * DZ);
  k_pad_rows<<<g1(64 * DZ), blk, 0, stream>>>(W2, w2p, DIM, 64 * DZ);
  k_pack_wihx<<<g1(G4 * DZ), blk, 0, stream>>>(Wih, wihx);
  k_pack_wcat<<<g1(G4 * KC), blk, 0, stream>>>(Wih, Whh, wcat);
  k_bias<<<16, blk, 0, stream>>>(bih, bhh, bsum, bp2, bp2p_, b2, b2p);
  k_init<<<g1(Bsz * H), blk, 0, stream>>>(c32, inpA);

  // G1: x = relu(x_in @ W_lin^T + b_lin)
  GArgs a{};
  a.A = xin16; a.ldA = DZ; a.Bm = wlin16; a.ldB = DZ; a.K = DZ;
  a.bias = blin; a.O = x16; a.ldO = DZ;
  gemm_k<64, 128, 32, 64, EPI_RELU_F16><<<dim3(Bsz / 64, 4), 256, 0, stream>>>(a);
  // G2: t = relu(x @ W_p1^T + b_p1)
  a.A = x16; a.Bm = wp1_16; a.bias = bp1; a.O = t16;
  gemm_k<64, 128, 32, 64, EPI_RELU_F16><<<dim3(Bsz / 64, 4), 256, 0, stream>>>(a);
  // G3: pose0 = t @ W_p2^T + b_p2 -> inpA pose region
  GArgs a3{};
  a3.A = t16; a3.ldA = DZ; a3.Bm = wp2p; a3.ldB = DZ; a3.K = DZ;
  a3.bias = bp2p_; a3.O = inpA + H; a3.ldO = KC;
  gemm_k<64, 64, 32, 32, EPI_F16><<<dim3(Bsz / 64, 1), 256, 0, stream>>>(a3);
  // G4: gates_x = x @ W_ihx^T + (b_ih + b_hh), stored f16 permuted [B][j][gate]
  GArgs a4{};
  a4.A = x16; a4.ldA = DZ; a4.Bm = wihx; a4.ldB = DZ; a4.K = DZ;
  a4.bias = bsum; a4.O = gx16;
  gemm_k<128, 128, 32, 128, EPI_GATESX><<<dim3(Bsz / 128, G4 / 128), 256, 0, stream>>>(a4);

  for (int t = 0; t < T; ++t) {
    f16* cur = (t & 1) ? inpB : inpA;
    f16* nxt = (t & 1) ? inpA : inpB;
    // S1: gates GEMM + fused LSTM cell -> h into nxt, c updated
    GArgs s1{};
    s1.A = cur; s1.ldA = KC; s1.Bm = wcat; s1.ldB = KC; s1.K = KC;
    s1.gx = gx16; s1.c32 = c32; s1.inp = nxt;
    gemm_k<128, 128, 32, 128, EPI_LSTM><<<dim3(Bsz / 128, H / 32), 256, 0, stream>>>(s1);
    // S2: t1 = relu(h @ W_1^T + b_1)
    GArgs s2{};
    s2.A = nxt; s2.ldA = KC; s2.Bm = w1_16; s2.ldB = H; s2.K = H;
    s2.bias = b1; s2.O = t16; s2.ldO = DZ;
    gemm_k<64, 128, 32, 64, EPI_RELU_F16><<<dim3(Bsz / 64, 4), 256, 0, stream>>>(s2);
    // S3: pose = t1 @ W_2^T + b_2 -> out[:, t, :] and nxt pose region
    GArgs s3{};
    s3.A = t16; s3.ldA = DZ; s3.Bm = w2p; s3.ldB = DZ; s3.K = DZ;
    s3.bias = b2p; s3.inp = nxt; s3.outp = out; s3.t = t;
    gemm_k<64, 64, 32, 32, EPI_POSE><<<dim3(Bsz / 64, 1), 256, 0, stream>>>(s3);
  }
}

// Round 4
// 8923.822 us; speedup vs baseline: 1.3554x; 1.3554x over previous
//
#include <hip/hip_runtime.h>
#include <hip/hip_bf16.h>

#define DEV __device__ __forceinline__

typedef _Float16 f16;
typedef _Float16 f16x8 __attribute__((ext_vector_type(8)));
typedef _Float16 f16x4 __attribute__((ext_vector_type(4)));
typedef float    f32x4 __attribute__((ext_vector_type(4)));

constexpr int Bsz = 4096;   // batch
constexpr int DZ  = 512;
constexpr int DIM = 63;
constexpr int T   = 120;
constexpr int H   = 1024;
constexpr int G4  = 4096;   // 4*H
constexpr int KC  = 1088;   // H + 64 (pose padded to 64)

DEV void gload16(f16* lds_p, const f16* g) {
  __builtin_amdgcn_global_load_lds(
      (const __attribute__((address_space(1))) unsigned int*)g,
      (__attribute__((address_space(3))) unsigned int*)lds_p, 16, 0, 0);
}

DEV float sigf(float x) { return 1.f / (1.f + __expf(-x)); }
DEV float tanh_fast(float x) { float e = __expf(2.f * x); return (e - 1.f) / (e + 1.f); }

enum { EPI_RELU_F16 = 0, EPI_F16 = 1, EPI_GATESX = 2, EPI_POSE = 4 };

struct GArgs {
  const f16* A;  int ldA;
  const f16* Bm; int ldB;
  int K;
  const float* bias;
  f16* O; int ldO;
  f16* inp;
  float* outp; int t;
};

// ---------- generic m97-style GEMM (prologue + S2/S3) ----------
template <int BM, int BN, int WM, int WN, int EPI>
__global__ __launch_bounds__((BM / WM) * (BN / WN) * 64)
void gemm_k(GArgs p) {
  constexpr int WN_CNT = BN / WN;
  constexpr int NW = (BM / WM) * WN_CNT;
  constexpr int NT = NW * 64;
  constexpr int MF = WM / 16, NF = WN / 16;
  constexpr int AIT = BM * 8 / NT, BIT = BN * 8 / NT;
  constexpr int RPI = NT / 8;

  __shared__ __align__(16) f16 sA[BM * 64];
  __shared__ __align__(16) f16 sB[BN * 64];

  const int tid = threadIdx.x, lane = tid & 63;
  const int wv = tid >> 6, wm = wv / WN_CNT, wn = wv % WN_CNT;
  const int bm = blockIdx.x, bn = blockIdx.y;

  f32x4 acc[MF][NF] = {};

  const int sr = tid >> 3;
  const int sc = (tid & 7) * 8;
  const f16* gA = p.A + (size_t)(bm * BM + sr) * p.ldA + sc;
  const f16* gB = p.Bm + (size_t)(bn * BN + sr) * p.ldB + sc;
  f16* lA = sA + tid * 8;
  f16* lB = sB + tid * 8;

  for (int k0 = 0; k0 < p.K; k0 += 64) {
#pragma unroll
    for (int it = 0; it < AIT; ++it)
      gload16(lA + it * NT * 8, gA + (size_t)it * RPI * p.ldA + k0);
#pragma unroll
    for (int it = 0; it < BIT; ++it)
      gload16(lB + it * NT * 8, gB + (size_t)it * RPI * p.ldB + k0);
    __syncthreads();
#pragma unroll
    for (int kk = 0; kk < 2; ++kk) {
      f16x8 af[MF], bf[NF];
#pragma unroll
      for (int i = 0; i < MF; ++i)
        af[i] = *(const f16x8*)(sA + (wm * WM + i * 16 + (lane & 15)) * 64 + kk * 32 + (lane >> 4) * 8);
#pragma unroll
      for (int j = 0; j < NF; ++j)
        bf[j] = *(const f16x8*)(sB + (wn * WN + j * 16 + (lane & 15)) * 64 + kk * 32 + (lane >> 4) * 8);
#pragma unroll
      for (int i = 0; i < MF; ++i)
#pragma unroll
        for (int j = 0; j < NF; ++j)
          acc[i][j] = __builtin_amdgcn_mfma_f32_16x16x32_f16(af[i], bf[j], acc[i][j], 0, 0, 0);
    }
    __syncthreads();
  }

  const int r0 = bm * BM + wm * WM;
  const int c0 = bn * BN + wn * WN;

  if constexpr (EPI == EPI_POSE) {
#pragma unroll
    for (int i = 0; i < MF; ++i)
#pragma unroll
      for (int j = 0; j < NF; ++j)
#pragma unroll
        for (int r = 0; r < 4; ++r) {
          const int row = r0 + i * 16 + ((lane >> 4) << 2) + r;
          const int col = c0 + j * 16 + (lane & 15);
          float v = acc[i][j][r] + p.bias[col];
          p.inp[(size_t)row * KC + H + col] = (f16)v;
          if (col < DIM)
            p.outp[(size_t)row * (T * DIM) + (size_t)p.t * DIM + col] = v;
        }
  } else {
#pragma unroll
    for (int i = 0; i < MF; ++i)
#pragma unroll
      for (int j = 0; j < NF; ++j)
#pragma unroll
        for (int r = 0; r < 4; ++r) {
          const int row = r0 + i * 16 + ((lane >> 4) << 2) + r;
          const int col = c0 + j * 16 + (lane & 15);
          float v = acc[i][j][r] + p.bias[col];
          if constexpr (EPI == EPI_RELU_F16) v = fmaxf(v, 0.f);
          if constexpr (EPI == EPI_GATESX)
            p.O[(size_t)row * G4 + ((size_t)(col & 1023) << 2) + (col >> 10)] = (f16)v;
          else
            p.O[(size_t)row * p.ldO + col] = (f16)v;
        }
  }
}

// ---------- S1: 256x256 8-phase gates GEMM + fused LSTM cell ----------
// A[4096,1088] f16 (inp = [h|pose]), Bw[4096,1088] f16 (wcat, rows = gate*1024+j),
// K = 1088 = 17 tiles of 64. 2-slot LDS dbuf, counted vmcnt, XOR-swizzled reads.
//
// vmcnt ledger (issue order per tile: A0,A2, B0,B1, B2,B3, A1,A3 — 8 loads):
//   p0 reads: A rows {wm*128+0..63} (chunks A0|A2 by wm) + B chunk wn  -> needs oldest 6 -> vmcnt(2)
//   p1 reads: B chunk wn (already covered)                              -> no wait
//   p2 reads: A rows {wm*128+64..127} (chunks A1|A3); outstanding = 2 old + 4 new -> vmcnt(4)
//   p3 reads: nothing (register-only MFMA)                              -> no wait
// WAITV precedes BARRIER, so per-wave vmcnt becomes collective at the rendezvous.

#define WAITV(N) asm volatile("s_waitcnt vmcnt(" #N ")" ::: "memory")
#define BARRIER()                          \
  {                                        \
    asm volatile("" ::: "memory");         \
    __builtin_amdgcn_s_barrier();          \
    asm volatile("" ::: "memory");         \
  }

#define RD_A(SLOT, MH, DST)                                                         \
  _Pragma("unroll") for (int fi = 0; fi < 4; ++fi)                                  \
  _Pragma("unroll") for (int kk = 0; kk < 2; ++kk)                                  \
      DST[fi * 2 + kk] = *(const f16x8*)(lds + (SLOT) * 32768 +                     \
          (mb + ((MH) * 4 + fi) * 16) * 64 + ((kk * 32 + ck0) ^ swf));

#define RD_B(SLOT, NH, DST)                                                         \
  _Pragma("unroll") for (int fj = 0; fj < 2; ++fj)                                  \
  _Pragma("unroll") for (int kk = 0; kk < 2; ++kk)                                  \
      DST[fj * 2 + kk] = *(const f16x8*)(lds + (SLOT) * 32768 + 16384 +             \
          (nb + ((NH) * 2 + fj) * 16) * 64 + ((kk * 32 + ck0) ^ swf));

#define MFMA8(MH, NH, A_, B_)                                                       \
  __builtin_amdgcn_s_setprio(1);                                                    \
  _Pragma("unroll") for (int kk = 0; kk < 2; ++kk)                                  \
  _Pragma("unroll") for (int fi = 0; fi < 4; ++fi)                                  \
  _Pragma("unroll") for (int fj = 0; fj < 2; ++fj)                                  \
      acc[(MH) * 4 + fi][(NH) * 2 + fj] = __builtin_amdgcn_mfma_f32_16x16x32_f16(   \
          A_[fi * 2 + kk], B_[fj * 2 + kk], acc[(MH) * 4 + fi][(NH) * 2 + fj], 0, 0, 0); \
  __builtin_amdgcn_s_setprio(0);

#define ST_A(D, IT, TILE) \
  gload16(ldsA + (D) * 32768 + (IT) * 4096, gA + (size_t)(64 * (IT)) * KC + (TILE) * 64)
#define ST_B(D, IT, TILE) \
  gload16(ldsB + (D) * 32768 + (IT) * 4096, gB + (size_t)(16 * (IT)) * KC + (TILE) * 64)

__global__ __launch_bounds__(512, 2)
void lstm_gates_8ph(const f16* __restrict__ A, const f16* __restrict__ Bw,
                    const f16* __restrict__ gx, float* __restrict__ c32,
                    f16* __restrict__ inp) {
  __shared__ __align__(16) f16 lds[65536];  // 128 KiB: [slot][A 16384 | B 16384]

  const int tid = threadIdx.x, lane = tid & 63;
  const int wv = tid >> 6, wm = wv >> 2, wn = wv & 3;
  const int bm = blockIdx.x, bn = blockIdx.y;

  // --- staging (per thread): LDS row rr(+64*it), 8 f16 at c0; linear dest, pre-swizzled src ---
  const int rr = tid >> 3;             // 0..63
  const int c0 = (tid & 7) * 8;
  const int swst = (rr & 7) << 3;      // row-XOR swizzle (f16 units)
  const int cs = c0 ^ swst;            // source col within tile
  const f16* gA = A + (size_t)(bm * 256 + rr) * KC + cs;
  const int grow0 = (tid >> 7) * 1024 + bn * 64 + ((tid >> 3) & 15);  // gate-major B row
  const f16* gB = Bw + (size_t)grow0 * KC + cs;
  f16* ldsA = lds + tid * 8;
  f16* ldsB = lds + 16384 + tid * 8;

  // --- fragment read addressing ---
  const int ck0 = (lane >> 4) * 8;
  const int swf = (lane & 7) << 3;
  const int mb = wm * 128 + (lane & 15);
  const int nb = wn * 64 + (lane & 15);

  f32x4 acc[8][4] = {};
  f16x8 afr[8], bfr0[4], bfr1[4];

  // prologue: stage tile 0 (slot 0) in ledger order A0,A2, B0..B3, A1,A3
  ST_A(0, 0, 0); ST_A(0, 2, 0);
  ST_B(0, 0, 0); ST_B(0, 1, 0);
  ST_B(0, 2, 0); ST_B(0, 3, 0);
  ST_A(0, 1, 0); ST_A(0, 3, 0);

  for (int kt = 0; kt < 16; ++kt) {
    const int s = kt & 1, d = s ^ 1, nt = kt + 1;
    // p0: quadrant (0,0) — needs A-low halves + all B of slot s
    WAITV(2); BARRIER();
    RD_A(s, 0, afr); RD_B(s, 0, bfr0);
    ST_A(d, 0, nt); ST_A(d, 2, nt);
    MFMA8(0, 0, afr, bfr0);
    // p1: quadrant (0,1)
    BARRIER();
    RD_B(s, 1, bfr1);
    ST_B(d, 0, nt); ST_B(d, 1, nt);
    MFMA8(0, 1, afr, bfr1);
    // p2: quadrant (1,1) — needs A-high halves of slot s
    WAITV(4); BARRIER();
    RD_A(s, 1, afr);
    ST_B(d, 2, nt); ST_B(d, 3, nt);
    MFMA8(1, 1, afr, bfr1);
    // p3: quadrant (1,0) — register-only
    BARRIER();
    ST_A(d, 1, nt); ST_A(d, 3, nt);
    MFMA8(1, 0, afr, bfr0);
  }

  // tail tile kt=16 (slot 0), drains 2 -> 0
  WAITV(2); BARRIER();
  RD_A(0, 0, afr); RD_B(0, 0, bfr0);
  MFMA8(0, 0, afr, bfr0);
  RD_B(0, 1, bfr1);
  MFMA8(0, 1, afr, bfr1);
  WAITV(0); BARRIER();
  RD_A(0, 1, afr);
  MFMA8(1, 1, afr, bfr1);
  MFMA8(1, 0, afr, bfr0);

  // --- fused LSTM cell epilogue ---
  // wave wn covers jg in [bn*64 + wn*16, +16); acc[i][g] = gate g (i,f,g,o)
  const int jg = (bn * 4 + wn) * 16 + (lane & 15);
  const int r0 = bm * 256 + wm * 128;
#pragma unroll
  for (int i = 0; i < 8; ++i) {
#pragma unroll
    for (int r = 0; r < 4; ++r) {
      const int row = r0 + i * 16 + ((lane >> 4) << 2) + r;
      f16x4 g4v = *(const f16x4*)(gx + (size_t)row * G4 + jg * 4);
      float ig = acc[i][0][r] + (float)g4v[0];
      float fg = acc[i][1][r] + (float)g4v[1];
      float gg = acc[i][2][r] + (float)g4v[2];
      float og = acc[i][3][r] + (float)g4v[3];
      float c = c32[(size_t)row * H + jg];
      c = sigf(fg) * c + sigf(ig) * tanh_fast(gg);
      float h = sigf(og) * tanh_fast(c);
      c32[(size_t)row * H + jg] = c;
      inp[(size_t)row * KC + jg] = (f16)h;
    }
  }
}

// ---------------- prologue helper kernels ----------------
__global__ void k_cvt(const float* s, f16* d, int n) {
  for (int i = blockIdx.x * blockDim.x + threadIdx.x; i < n; i += gridDim.x * blockDim.x)
    d[i] = (f16)s[i];
}
__global__ void k_pad_rows(const float* s, f16* d, int rows, int n) {
  for (int i = blockIdx.x * blockDim.x + threadIdx.x; i < n; i += gridDim.x * blockDim.x) {
    int r = i >> 9;
    d[i] = (r < rows) ? (f16)s[i] : (f16)0.f;
  }
}
__global__ void k_pack_wihx(const float* W, f16* d) {
  for (int i = blockIdx.x * blockDim.x + threadIdx.x; i < G4 * DZ; i += gridDim.x * blockDim.x) {
    int n = i >> 9, k = i & 511;
    d[i] = (f16)W[n * 575 + k];
  }
}
__global__ void k_pack_wcat(const float* Wih, const float* Whh, f16* d) {
  for (int i = blockIdx.x * blockDim.x + threadIdx.x; i < G4 * KC; i += gridDim.x * blockDim.x) {
    int n = i / KC, k = i - n * KC;
    float v = (k < H) ? Whh[n * H + k] : ((k < H + DIM) ? Wih[n * 575 + DZ + (k - H)] : 0.f);
    d[i] = (f16)v;
  }
}
__global__ void k_bias(const float* bih, const float* bhh, float* bsum,
                       const float* bp2, float* bp2p, const float* b2, float* b2p) {
  int i = blockIdx.x * blockDim.x + threadIdx.x;
  if (i < G4) bsum[i] = bih[i] + bhh[i];
  if (i < 64) {
    bp2p[i] = (i < DIM) ? bp2[i] : 0.f;
    b2p[i]  = (i < DIM) ? b2[i]  : 0.f;
  }
}
__global__ void k_init(float* c32, f16* inp) {
  for (int i = blockIdx.x * blockDim.x + threadIdx.x; i < Bsz * H; i += gridDim.x * blockDim.x) {
    c32[i] = 0.f;
    inp[(size_t)(i >> 10) * KC + (i & 1023)] = (f16)0.f;
  }
}

extern "C" void kernel_launch(void* const* d_in, const int* in_sizes, int n_in,
                              void* d_out, int out_size, void* d_ws, size_t ws_size,
                              hipStream_t stream) {
  const float* x_in = (const float*)d_in[0];
  const float* Wlin = (const float*)d_in[1];
  const float* blin = (const float*)d_in[2];
  const float* Wp1  = (const float*)d_in[3];
  const float* bp1  = (const float*)d_in[4];
  const float* Wp2  = (const float*)d_in[5];
  const float* bp2  = (const float*)d_in[6];
  const float* Wih  = (const float*)d_in[7];
  const float* bih  = (const float*)d_in[8];
  const float* Whh  = (const float*)d_in[9];
  const float* bhh  = (const float*)d_in[10];
  const float* W1   = (const float*)d_in[11];
  const float* b1   = (const float*)d_in[12];
  const float* W2   = (const float*)d_in[13];
  const float* b2   = (const float*)d_in[14];
  float* out = (float*)d_out;

  char* w = (char*)d_ws;
  auto alloc = [&](size_t bytes) { char* r = w; w += (bytes + 255) & ~(size_t)255; return r; };
  f16*   inpA   = (f16*)alloc((size_t)Bsz * KC * 2);
  f16*   inpB   = (f16*)alloc((size_t)Bsz * KC * 2);
  float* c32    = (float*)alloc((size_t)Bsz * H * 4);
  f16*   gx16   = (f16*)alloc((size_t)Bsz * G4 * 2);
  f16*   wcat   = (f16*)alloc((size_t)G4 * KC * 2);
  f16*   wihx   = (f16*)alloc((size_t)G4 * DZ * 2);
  f16*   wlin16 = (f16*)alloc((size_t)DZ * DZ * 2);
  f16*   wp1_16 = (f16*)alloc((size_t)DZ * DZ * 2);
  f16*   wp2p   = (f16*)alloc((size_t)64 * DZ * 2);
  f16*   w1_16  = (f16*)alloc((size_t)DZ * H * 2);
  f16*   w2p    = (f16*)alloc((size_t)64 * DZ * 2);
  f16*   xin16  = (f16*)alloc((size_t)Bsz * DZ * 2);
  f16*   x16    = (f16*)alloc((size_t)Bsz * DZ * 2);
  f16*   t16    = (f16*)alloc((size_t)Bsz * DZ * 2);
  float* bsum   = (float*)alloc((size_t)G4 * 4);
  float* bp2p_  = (float*)alloc(64 * 4);
  float* b2p    = (float*)alloc(64 * 4);

  dim3 blk(256);
  auto g1 = [](int n) { int b = (n + 255) / 256; return dim3(b > 2048 ? 2048 : b); };

  k_cvt<<<g1(Bsz * DZ), blk, 0, stream>>>(x_in, xin16, Bsz * DZ);
  k_cvt<<<g1(DZ * DZ), blk, 0, stream>>>(Wlin, wlin16, DZ * DZ);
  k_cvt<<<g1(DZ * DZ), blk, 0, stream>>>(Wp1, wp1_16, DZ * DZ);
  k_cvt<<<g1(DZ * H), blk, 0, stream>>>(W1, w1_16, DZ * H);
  k_pad_rows<<<g1(64 * DZ), blk, 0, stream>>>(Wp2, wp2p, DIM, 64 * DZ);
  k_pad_rows<<<g1(64 * DZ), blk, 0, stream>>>(W2, w2p, DIM, 64 * DZ);
  k_pack_wihx<<<g1(G4 * DZ), blk, 0, stream>>>(Wih, wihx);
  k_pack_wcat<<<g1(G4 * KC), blk, 0, stream>>>(Wih, Whh, wcat);
  k_bias<<<16, blk, 0, stream>>>(bih, bhh, bsum, bp2, bp2p_, b2, b2p);
  k_init<<<g1(Bsz * H), blk, 0, stream>>>(c32, inpA);

  // G1: x = relu(x_in @ W_lin^T + b_lin)
  GArgs a{};
  a.A = xin16; a.ldA = DZ; a.Bm = wlin16; a.ldB = DZ; a.K = DZ;
  a.bias = blin; a.O = x16; a.ldO = DZ;
  gemm_k<64, 128, 32, 64, EPI_RELU_F16><<<dim3(Bsz / 64, 4), 256, 0, stream>>>(a);
  // G2: t = relu(x @ W_p1^T + b_p1)
  a.A = x16; a.Bm = wp1_16; a.bias = bp1; a.O = t16;
  gemm_k<64, 128, 32, 64, EPI_RELU_F16><<<dim3(Bsz / 64, 4), 256, 0, stream>>>(a);
  // G3: pose0 = t @ W_p2^T + b_p2 -> inpA pose region
  GArgs a3{};
  a3.A = t16; a3.ldA = DZ; a3.Bm = wp2p; a3.ldB = DZ; a3.K = DZ;
  a3.bias = bp2p_; a3.O = inpA + H; a3.ldO = KC;
  gemm_k<64, 64, 32, 32, EPI_F16><<<dim3(Bsz / 64, 1), 256, 0, stream>>>(a3);
  // G4: gates_x = x @ W_ihx^T + (b_ih + b_hh), stored f16 permuted [row][j*4+gate]
  GArgs a4{};
  a4.A = x16; a4.ldA = DZ; a4.Bm = wihx; a4.ldB = DZ; a4.K = DZ;
  a4.bias = bsum; a4.O = gx16;
  gemm_k<128, 128, 32, 128, EPI_GATESX><<<dim3(Bsz / 128, G4 / 128), 256, 0, stream>>>(a4);

  for (int t = 0; t < T; ++t) {
    f16* cur = (t & 1) ? inpB : inpA;
    f16* nxt = (t & 1) ? inpA : inpB;
    // S1: 8-phase gates GEMM + fused LSTM cell -> h into nxt, c updated
    lstm_gates_8ph<<<dim3(16, 16), 512, 0, stream>>>(cur, wcat, gx16, c32, nxt);
    // S2: t1 = relu(h @ W_1^T + b_1)
    GArgs s2{};
    s2.A = nxt; s2.ldA = KC; s2.Bm = w1_16; s2.ldB = H; s2.K = H;
    s2.bias = b1; s2.O = t16; s2.ldO = DZ;
    gemm_k<64, 128, 32, 64, EPI_RELU_F16><<<dim3(Bsz / 64, 4), 256, 0, stream>>>(s2);
    // S3: pose = t1 @ W_2^T + b_2 -> out[:, t, :] and nxt pose region
    GArgs s3{};
    s3.A = t16; s3.ldA = DZ; s3.Bm = w2p; s3.ldB = DZ; s3.K = DZ;
    s3.bias = b2p; s3.inp = nxt; s3.outp = out; s3.t = t;
    gemm_k<64, 64, 32, 32, EPI_POSE><<<dim3(Bsz / 64, 1), 256, 0, stream>>>(s3);
  }
}

// Round 5
// 8516.016 us; speedup vs baseline: 1.4203x; 1.0479x over previous
//
#include <hip/hip_runtime.h>
#include <hip/hip_bf16.h>

#define DEV __device__ __forceinline__

typedef _Float16 f16;
typedef _Float16 f16x8 __attribute__((ext_vector_type(8)));
typedef _Float16 f16x4 __attribute__((ext_vector_type(4)));
typedef float    f32x4 __attribute__((ext_vector_type(4)));

constexpr int Bsz = 4096;   // batch
constexpr int DZ  = 512;
constexpr int DIM = 63;
constexpr int T   = 120;
constexpr int H   = 1024;
constexpr int G4  = 4096;   // 4*H
constexpr int KC  = 1088;   // H + 64 (pose padded to 64)

DEV void gload16(f16* lds_p, const f16* g) {
  __builtin_amdgcn_global_load_lds(
      (const __attribute__((address_space(1))) unsigned int*)g,
      (__attribute__((address_space(3))) unsigned int*)lds_p, 16, 0, 0);
}

DEV float sigf(float x) { return 1.f / (1.f + __expf(-x)); }
DEV float tanh_fast(float x) { float e = __expf(2.f * x); return (e - 1.f) / (e + 1.f); }

enum { EPI_RELU_F16 = 0, EPI_F16 = 1, EPI_GATESX = 2, EPI_POSE = 4 };

struct GArgs {
  const f16* A;  int ldA;
  const f16* Bm; int ldB;
  int K;
  const float* bias;
  f16* O; int ldO;
  f16* inp;
  float* outp; int t;
};

// ---------- generic m97-style GEMM (prologue + S2/S3) ----------
template <int BM, int BN, int WM, int WN, int EPI>
__global__ __launch_bounds__((BM / WM) * (BN / WN) * 64)
void gemm_k(GArgs p) {
  constexpr int WN_CNT = BN / WN;
  constexpr int NW = (BM / WM) * WN_CNT;
  constexpr int NT = NW * 64;
  constexpr int MF = WM / 16, NF = WN / 16;
  constexpr int AIT = BM * 8 / NT, BIT = BN * 8 / NT;
  constexpr int RPI = NT / 8;

  __shared__ __align__(16) f16 sA[BM * 64];
  __shared__ __align__(16) f16 sB[BN * 64];

  const int tid = threadIdx.x, lane = tid & 63;
  const int wv = tid >> 6, wm = wv / WN_CNT, wn = wv % WN_CNT;
  const int bm = blockIdx.x, bn = blockIdx.y;

  f32x4 acc[MF][NF] = {};

  const int sr = tid >> 3;
  const int sc = (tid & 7) * 8;
  const f16* gA = p.A + (size_t)(bm * BM + sr) * p.ldA + sc;
  const f16* gB = p.Bm + (size_t)(bn * BN + sr) * p.ldB + sc;
  f16* lA = sA + tid * 8;
  f16* lB = sB + tid * 8;

  for (int k0 = 0; k0 < p.K; k0 += 64) {
#pragma unroll
    for (int it = 0; it < AIT; ++it)
      gload16(lA + it * NT * 8, gA + (size_t)it * RPI * p.ldA + k0);
#pragma unroll
    for (int it = 0; it < BIT; ++it)
      gload16(lB + it * NT * 8, gB + (size_t)it * RPI * p.ldB + k0);
    __syncthreads();
#pragma unroll
    for (int kk = 0; kk < 2; ++kk) {
      f16x8 af[MF], bf[NF];
#pragma unroll
      for (int i = 0; i < MF; ++i)
        af[i] = *(const f16x8*)(sA + (wm * WM + i * 16 + (lane & 15)) * 64 + kk * 32 + (lane >> 4) * 8);
#pragma unroll
      for (int j = 0; j < NF; ++j)
        bf[j] = *(const f16x8*)(sB + (wn * WN + j * 16 + (lane & 15)) * 64 + kk * 32 + (lane >> 4) * 8);
#pragma unroll
      for (int i = 0; i < MF; ++i)
#pragma unroll
        for (int j = 0; j < NF; ++j)
          acc[i][j] = __builtin_amdgcn_mfma_f32_16x16x32_f16(af[i], bf[j], acc[i][j], 0, 0, 0);
    }
    __syncthreads();
  }

  const int r0 = bm * BM + wm * WM;
  const int c0 = bn * BN + wn * WN;

  if constexpr (EPI == EPI_POSE) {
#pragma unroll
    for (int i = 0; i < MF; ++i)
#pragma unroll
      for (int j = 0; j < NF; ++j)
#pragma unroll
        for (int r = 0; r < 4; ++r) {
          const int row = r0 + i * 16 + ((lane >> 4) << 2) + r;
          const int col = c0 + j * 16 + (lane & 15);
          float v = acc[i][j][r] + p.bias[col];
          p.inp[(size_t)row * KC + H + col] = (f16)v;
          if (col < DIM)
            p.outp[(size_t)row * (T * DIM) + (size_t)p.t * DIM + col] = v;
        }
  } else {
#pragma unroll
    for (int i = 0; i < MF; ++i)
#pragma unroll
      for (int j = 0; j < NF; ++j)
#pragma unroll
        for (int r = 0; r < 4; ++r) {
          const int row = r0 + i * 16 + ((lane >> 4) << 2) + r;
          const int col = c0 + j * 16 + (lane & 15);
          float v = acc[i][j][r] + p.bias[col];
          if constexpr (EPI == EPI_RELU_F16) v = fmaxf(v, 0.f);
          if constexpr (EPI == EPI_GATESX)
            p.O[(size_t)row * G4 + ((size_t)(col & 1023) << 2) + (col >> 10)] = (f16)v;
          else
            p.O[(size_t)row * p.ldO + col] = (f16)v;
        }
  }
}

// ---------- S1: 256x256 8-phase gates GEMM + fused LSTM cell ----------
// A[4096,1088] f16 (inp = [h|pose]), Bw[4096,1088] f16 (wcat, rows = gate*1024+j),
// K = 1088 = 17 tiles of 64. 2-slot LDS dbuf, counted vmcnt, XOR-swizzled reads.
//
// vmcnt ledger (issue order per tile: A0,A2 @p0 | B0,B1,B2,B3 @p1 | A1,A3 @p2 | p3 none):
//   p0 reads A-low chunks {A0|A2 by wm} + B chunk wn of CURRENT tile.
//     Entering p0, outstanding = {A1,A3} of current tile (issued prev p2) -> vmcnt(2).
//     Min prefetch distance: B chunks issued prev p1 -> 3 phases ahead (was 2).
//   p1 reads B chunk wn (covered by p0's wait) -> no wait.
//   p2 reads A-high {A1|A3}: issued since p0 = A0,A2 (p0) + B0..B3 (p1) = 6 -> vmcnt(6).
//     A-high issued prev p2 -> 4 phases ahead (was 3).
//   p3: register-only MFMA -> no wait. Max 8 loads in flight.
// WAITV precedes BARRIER, so per-wave vmcnt becomes collective at the rendezvous.

#define WAITV(N) asm volatile("s_waitcnt vmcnt(" #N ")" ::: "memory")
#define BARRIER()                          \
  {                                        \
    asm volatile("" ::: "memory");         \
    __builtin_amdgcn_s_barrier();          \
    asm volatile("" ::: "memory");         \
  }

#define RD_A(SLOT, MH, DST)                                                         \
  _Pragma("unroll") for (int fi = 0; fi < 4; ++fi)                                  \
  _Pragma("unroll") for (int kk = 0; kk < 2; ++kk)                                  \
      DST[fi * 2 + kk] = *(const f16x8*)(lds + (SLOT) * 32768 +                     \
          (mb + ((MH) * 4 + fi) * 16) * 64 + ((kk * 32 + ck0) ^ swf));

#define RD_B(SLOT, NH, DST)                                                         \
  _Pragma("unroll") for (int fj = 0; fj < 2; ++fj)                                  \
  _Pragma("unroll") for (int kk = 0; kk < 2; ++kk)                                  \
      DST[fj * 2 + kk] = *(const f16x8*)(lds + (SLOT) * 32768 + 16384 +             \
          (nb + ((NH) * 2 + fj) * 16) * 64 + ((kk * 32 + ck0) ^ swf));

#define MFMA8(MH, NH, A_, B_)                                                       \
  __builtin_amdgcn_s_setprio(1);                                                    \
  _Pragma("unroll") for (int kk = 0; kk < 2; ++kk)                                  \
  _Pragma("unroll") for (int fi = 0; fi < 4; ++fi)                                  \
  _Pragma("unroll") for (int fj = 0; fj < 2; ++fj)                                  \
      acc[(MH) * 4 + fi][(NH) * 2 + fj] = __builtin_amdgcn_mfma_f32_16x16x32_f16(   \
          A_[fi * 2 + kk], B_[fj * 2 + kk], acc[(MH) * 4 + fi][(NH) * 2 + fj], 0, 0, 0); \
  __builtin_amdgcn_s_setprio(0);

#define ST_A(D, IT, TILE) \
  gload16(ldsA + (D) * 32768 + (IT) * 4096, gA + (size_t)(64 * (IT)) * KC + (TILE) * 64)
#define ST_B(D, IT, TILE) \
  gload16(ldsB + (D) * 32768 + (IT) * 4096, gB + (size_t)(16 * (IT)) * KC + (TILE) * 64)

__global__ __launch_bounds__(512, 2)
void lstm_gates_8ph(const f16* __restrict__ A, const f16* __restrict__ Bw,
                    const f16* __restrict__ gx, float* __restrict__ c32,
                    f16* __restrict__ inp) {
  __shared__ __align__(16) f16 lds[65536];  // 128 KiB: [slot][A 16384 | B 16384]

  const int tid = threadIdx.x, lane = tid & 63;
  const int wv = tid >> 6, wm = wv >> 2, wn = wv & 3;
  const int bm = blockIdx.x, bn = blockIdx.y;

  // --- staging (per thread): LDS row rr(+64*it), 8 f16 at c0; linear dest, pre-swizzled src ---
  const int rr = tid >> 3;             // 0..63
  const int c0 = (tid & 7) * 8;
  const int swst = (rr & 7) << 3;      // row-XOR swizzle (f16 units)
  const int cs = c0 ^ swst;            // source col within tile
  const f16* gA = A + (size_t)(bm * 256 + rr) * KC + cs;
  const int grow0 = (tid >> 7) * 1024 + bn * 64 + ((tid >> 3) & 15);  // gate-major B row
  const f16* gB = Bw + (size_t)grow0 * KC + cs;
  f16* ldsA = lds + tid * 8;
  f16* ldsB = lds + 16384 + tid * 8;

  // --- fragment read addressing ---
  const int ck0 = (lane >> 4) * 8;
  const int swf = (lane & 7) << 3;
  const int mb = wm * 128 + (lane & 15);
  const int nb = wn * 64 + (lane & 15);

  f32x4 acc[8][4] = {};
  f16x8 afr[8], bfr0[4], bfr1[4];

  // prologue: stage tile 0 (slot 0) in ledger order A0,A2, B0..B3, A1,A3
  ST_A(0, 0, 0); ST_A(0, 2, 0);
  ST_B(0, 0, 0); ST_B(0, 1, 0);
  ST_B(0, 2, 0); ST_B(0, 3, 0);
  ST_A(0, 1, 0); ST_A(0, 3, 0);

  for (int kt = 0; kt < 16; ++kt) {
    const int s = kt & 1, d = s ^ 1, nt = kt + 1;
    // p0: quadrant (0,0) — needs A-low halves + all B of slot s
    WAITV(2); BARRIER();
    RD_A(s, 0, afr); RD_B(s, 0, bfr0);
    ST_A(d, 0, nt); ST_A(d, 2, nt);
    MFMA8(0, 0, afr, bfr0);
    // p1: quadrant (0,1) — stage ALL B chunks (3-phase lead to next p0)
    BARRIER();
    RD_B(s, 1, bfr1);
    ST_B(d, 0, nt); ST_B(d, 1, nt);
    ST_B(d, 2, nt); ST_B(d, 3, nt);
    MFMA8(0, 1, afr, bfr1);
    // p2: quadrant (1,1) — needs A-high halves of slot s; stage A-high (4-phase lead)
    WAITV(6); BARRIER();
    RD_A(s, 1, afr);
    ST_A(d, 1, nt); ST_A(d, 3, nt);
    MFMA8(1, 1, afr, bfr1);
    // p3: quadrant (1,0) — register-only
    BARRIER();
    MFMA8(1, 0, afr, bfr0);
  }

  // tail tile kt=16 (slot 0), drains 2 -> 0
  WAITV(2); BARRIER();
  RD_A(0, 0, afr); RD_B(0, 0, bfr0);
  MFMA8(0, 0, afr, bfr0);
  RD_B(0, 1, bfr1);
  MFMA8(0, 1, afr, bfr1);
  WAITV(0); BARRIER();
  RD_A(0, 1, afr);
  MFMA8(1, 1, afr, bfr1);
  MFMA8(1, 0, afr, bfr0);

  // --- fused LSTM cell epilogue ---
  // wave wn covers jg in [bn*64 + wn*16, +16); acc[i][g] = gate g (i,f,g,o)
  const int jg = (bn * 4 + wn) * 16 + (lane & 15);
  const int r0 = bm * 256 + wm * 128;
#pragma unroll
  for (int i = 0; i < 8; ++i) {
#pragma unroll
    for (int r = 0; r < 4; ++r) {
      const int row = r0 + i * 16 + ((lane >> 4) << 2) + r;
      f16x4 g4v = *(const f16x4*)(gx + (size_t)row * G4 + jg * 4);
      float ig = acc[i][0][r] + (float)g4v[0];
      float fg = acc[i][1][r] + (float)g4v[1];
      float gg = acc[i][2][r] + (float)g4v[2];
      float og = acc[i][3][r] + (float)g4v[3];
      float c = c32[(size_t)row * H + jg];
      c = sigf(fg) * c + sigf(ig) * tanh_fast(gg);
      float h = sigf(og) * tanh_fast(c);
      c32[(size_t)row * H + jg] = c;
      inp[(size_t)row * KC + jg] = (f16)h;
    }
  }
}

// ---------------- prologue helper kernels ----------------
__global__ void k_cvt(const float* s, f16* d, int n) {
  for (int i = blockIdx.x * blockDim.x + threadIdx.x; i < n; i += gridDim.x * blockDim.x)
    d[i] = (f16)s[i];
}
__global__ void k_pad_rows(const float* s, f16* d, int rows, int n) {
  for (int i = blockIdx.x * blockDim.x + threadIdx.x; i < n; i += gridDim.x * blockDim.x) {
    int r = i >> 9;
    d[i] = (r < rows) ? (f16)s[i] : (f16)0.f;
  }
}
__global__ void k_pack_wihx(const float* W, f16* d) {
  for (int i = blockIdx.x * blockDim.x + threadIdx.x; i < G4 * DZ; i += gridDim.x * blockDim.x) {
    int n = i >> 9, k = i & 511;
    d[i] = (f16)W[n * 575 + k];
  }
}
__global__ void k_pack_wcat(const float* Wih, const float* Whh, f16* d) {
  for (int i = blockIdx.x * blockDim.x + threadIdx.x; i < G4 * KC; i += gridDim.x * blockDim.x) {
    int n = i / KC, k = i - n * KC;
    float v = (k < H) ? Whh[n * H + k] : ((k < H + DIM) ? Wih[n * 575 + DZ + (k - H)] : 0.f);
    d[i] = (f16)v;
  }
}
__global__ void k_bias(const float* bih, const float* bhh, float* bsum,
                       const float* bp2, float* bp2p, const float* b2, float* b2p) {
  int i = blockIdx.x * blockDim.x + threadIdx.x;
  if (i < G4) bsum[i] = bih[i] + bhh[i];
  if (i < 64) {
    bp2p[i] = (i < DIM) ? bp2[i] : 0.f;
    b2p[i]  = (i < DIM) ? b2[i]  : 0.f;
  }
}
__global__ void k_init(float* c32, f16* inp) {
  for (int i = blockIdx.x * blockDim.x + threadIdx.x; i < Bsz * H; i += gridDim.x * blockDim.x) {
    c32[i] = 0.f;
    inp[(size_t)(i >> 10) * KC + (i & 1023)] = (f16)0.f;
  }
}

extern "C" void kernel_launch(void* const* d_in, const int* in_sizes, int n_in,
                              void* d_out, int out_size, void* d_ws, size_t ws_size,
                              hipStream_t stream) {
  const float* x_in = (const float*)d_in[0];
  const float* Wlin = (const float*)d_in[1];
  const float* blin = (const float*)d_in[2];
  const float* Wp1  = (const float*)d_in[3];
  const float* bp1  = (const float*)d_in[4];
  const float* Wp2  = (const float*)d_in[5];
  const float* bp2  = (const float*)d_in[6];
  const float* Wih  = (const float*)d_in[7];
  const float* bih  = (const float*)d_in[8];
  const float* Whh  = (const float*)d_in[9];
  const float* bhh  = (const float*)d_in[10];
  const float* W1   = (const float*)d_in[11];
  const float* b1   = (const float*)d_in[12];
  const float* W2   = (const float*)d_in[13];
  const float* b2   = (const float*)d_in[14];
  float* out = (float*)d_out;

  char* w = (char*)d_ws;
  auto alloc = [&](size_t bytes) { char* r = w; w += (bytes + 255) & ~(size_t)255; return r; };
  f16*   inpA   = (f16*)alloc((size_t)Bsz * KC * 2);
  f16*   inpB   = (f16*)alloc((size_t)Bsz * KC * 2);
  float* c32    = (float*)alloc((size_t)Bsz * H * 4);
  f16*   gx16   = (f16*)alloc((size_t)Bsz * G4 * 2);
  f16*   wcat   = (f16*)alloc((size_t)G4 * KC * 2);
  f16*   wihx   = (f16*)alloc((size_t)G4 * DZ * 2);
  f16*   wlin16 = (f16*)alloc((size_t)DZ * DZ * 2);
  f16*   wp1_16 = (f16*)alloc((size_t)DZ * DZ * 2);
  f16*   wp2p   = (f16*)alloc((size_t)64 * DZ * 2);
  f16*   w1_16  = (f16*)alloc((size_t)DZ * H * 2);
  f16*   w2p    = (f16*)alloc((size_t)64 * DZ * 2);
  f16*   xin16  = (f16*)alloc((size_t)Bsz * DZ * 2);
  f16*   x16    = (f16*)alloc((size_t)Bsz * DZ * 2);
  f16*   t16    = (f16*)alloc((size_t)Bsz * DZ * 2);
  float* bsum   = (float*)alloc((size_t)G4 * 4);
  float* bp2p_  = (float*)alloc(64 * 4);
  float* b2p    = (float*)alloc(64 * 4);

  dim3 blk(256);
  auto g1 = [](int n) { int b = (n + 255) / 256; return dim3(b > 2048 ? 2048 : b); };

  k_cvt<<<g1(Bsz * DZ), blk, 0, stream>>>(x_in, xin16, Bsz * DZ);
  k_cvt<<<g1(DZ * DZ), blk, 0, stream>>>(Wlin, wlin16, DZ * DZ);
  k_cvt<<<g1(DZ * DZ), blk, 0, stream>>>(Wp1, wp1_16, DZ * DZ);
  k_cvt<<<g1(DZ * H), blk, 0, stream>>>(W1, w1_16, DZ * H);
  k_pad_rows<<<g1(64 * DZ), blk, 0, stream>>>(Wp2, wp2p, DIM, 64 * DZ);
  k_pad_rows<<<g1(64 * DZ), blk, 0, stream>>>(W2, w2p, DIM, 64 * DZ);
  k_pack_wihx<<<g1(G4 * DZ), blk, 0, stream>>>(Wih, wihx);
  k_pack_wcat<<<g1(G4 * KC), blk, 0, stream>>>(Wih, Whh, wcat);
  k_bias<<<16, blk, 0, stream>>>(bih, bhh, bsum, bp2, bp2p_, b2, b2p);
  k_init<<<g1(Bsz * H), blk, 0, stream>>>(c32, inpA);

  // G1: x = relu(x_in @ W_lin^T + b_lin)
  GArgs a{};
  a.A = xin16; a.ldA = DZ; a.Bm = wlin16; a.ldB = DZ; a.K = DZ;
  a.bias = blin; a.O = x16; a.ldO = DZ;
  gemm_k<64, 128, 32, 64, EPI_RELU_F16><<<dim3(Bsz / 64, 4), 256, 0, stream>>>(a);
  // G2: t = relu(x @ W_p1^T + b_p1)
  a.A = x16; a.Bm = wp1_16; a.bias = bp1; a.O = t16;
  gemm_k<64, 128, 32, 64, EPI_RELU_F16><<<dim3(Bsz / 64, 4), 256, 0, stream>>>(a);
  // G3: pose0 = t @ W_p2^T + b_p2 -> inpA pose region
  GArgs a3{};
  a3.A = t16; a3.ldA = DZ; a3.Bm = wp2p; a3.ldB = DZ; a3.K = DZ;
  a3.bias = bp2p_; a3.O = inpA + H; a3.ldO = KC;
  gemm_k<64, 64, 32, 32, EPI_F16><<<dim3(Bsz / 64, 1), 256, 0, stream>>>(a3);
  // G4: gates_x = x @ W_ihx^T + (b_ih + b_hh), stored f16 permuted [row][j*4+gate]
  GArgs a4{};
  a4.A = x16; a4.ldA = DZ; a4.Bm = wihx; a4.ldB = DZ; a4.K = DZ;
  a4.bias = bsum; a4.O = gx16;
  gemm_k<128, 128, 32, 128, EPI_GATESX><<<dim3(Bsz / 128, G4 / 128), 256, 0, stream>>>(a4);

  for (int t = 0; t < T; ++t) {
    f16* cur = (t & 1) ? inpB : inpA;
    f16* nxt = (t & 1) ? inpA : inpB;
    // S1: 8-phase gates GEMM + fused LSTM cell -> h into nxt, c updated
    lstm_gates_8ph<<<dim3(16, 16), 512, 0, stream>>>(cur, wcat, gx16, c32, nxt);
    // S2: t1 = relu(h @ W_1^T + b_1)
    GArgs s2{};
    s2.A = nxt; s2.ldA = KC; s2.Bm = w1_16; s2.ldB = H; s2.K = H;
    s2.bias = b1; s2.O = t16; s2.ldO = DZ;
    gemm_k<64, 128, 32, 64, EPI_RELU_F16><<<dim3(Bsz / 64, 4), 256, 0, stream>>>(s2);
    // S3: pose = t1 @ W_2^T + b_2 -> out[:, t, :] and nxt pose region
    // 128 blocks (was 64): same per-element K accumulation order, bit-identical output
    GArgs s3{};
    s3.A = t16; s3.ldA = DZ; s3.Bm = w2p; s3.ldB = DZ; s3.K = DZ;
    s3.bias = b2p; s3.inp = nxt; s3.outp = out; s3.t = t;
    gemm_k<32, 64, 16, 32, EPI_POSE><<<dim3(Bsz / 32, 1), 256, 0, stream>>>(s3);
  }
}

// Round 7
// 7714.368 us; speedup vs baseline: 1.5678x; 1.1039x over previous
//
#include <hip/hip_runtime.h>
#include <hip/hip_bf16.h>

#define DEV __device__ __forceinline__

typedef _Float16 f16;
typedef _Float16 f16x8 __attribute__((ext_vector_type(8)));
typedef _Float16 f16x4 __attribute__((ext_vector_type(4)));
typedef float    f32x4 __attribute__((ext_vector_type(4)));

constexpr int Bsz = 4096;   // batch
constexpr int DZ  = 512;
constexpr int DIM = 63;
constexpr int T   = 120;
constexpr int H   = 1024;
constexpr int G4  = 4096;   // 4*H
constexpr int KC  = 1088;   // H + 64 (pose padded to 64)

DEV void gload16(f16* lds_p, const f16* g) {
  __builtin_amdgcn_global_load_lds(
      (const __attribute__((address_space(1))) unsigned int*)g,
      (__attribute__((address_space(3))) unsigned int*)lds_p, 16, 0, 0);
}

DEV float sigf(float x) { return 1.f / (1.f + __expf(-x)); }
DEV float tanh_fast(float x) { float e = __expf(2.f * x); return (e - 1.f) / (e + 1.f); }

enum { EPI_RELU_F16 = 0, EPI_F16 = 1, EPI_GATESX = 2, EPI_POSE = 4 };

struct GArgs {
  const f16* A;  int ldA;
  const f16* Bm; int ldB;
  int K;
  const float* bias;
  f16* O; int ldO;
  f16* inp;
  float* outp; int t;
};

// ---------- generic m97-style GEMM (prologue only) ----------
template <int BM, int BN, int WM, int WN, int EPI>
__global__ __launch_bounds__((BM / WM) * (BN / WN) * 64)
void gemm_k(GArgs p) {
  constexpr int WN_CNT = BN / WN;
  constexpr int NW = (BM / WM) * WN_CNT;
  constexpr int NT = NW * 64;
  constexpr int MF = WM / 16, NF = WN / 16;
  constexpr int AIT = BM * 8 / NT, BIT = BN * 8 / NT;
  constexpr int RPI = NT / 8;

  __shared__ __align__(16) f16 sA[BM * 64];
  __shared__ __align__(16) f16 sB[BN * 64];

  const int tid = threadIdx.x, lane = tid & 63;
  const int wv = tid >> 6, wm = wv / WN_CNT, wn = wv % WN_CNT;
  const int bm = blockIdx.x, bn = blockIdx.y;

  f32x4 acc[MF][NF] = {};

  const int sr = tid >> 3;
  const int sc = (tid & 7) * 8;
  const f16* gA = p.A + (size_t)(bm * BM + sr) * p.ldA + sc;
  const f16* gB = p.Bm + (size_t)(bn * BN + sr) * p.ldB + sc;
  f16* lA = sA + tid * 8;
  f16* lB = sB + tid * 8;

  for (int k0 = 0; k0 < p.K; k0 += 64) {
#pragma unroll
    for (int it = 0; it < AIT; ++it)
      gload16(lA + it * NT * 8, gA + (size_t)it * RPI * p.ldA + k0);
#pragma unroll
    for (int it = 0; it < BIT; ++it)
      gload16(lB + it * NT * 8, gB + (size_t)it * RPI * p.ldB + k0);
    __syncthreads();
#pragma unroll
    for (int kk = 0; kk < 2; ++kk) {
      f16x8 af[MF], bf[NF];
#pragma unroll
      for (int i = 0; i < MF; ++i)
        af[i] = *(const f16x8*)(sA + (wm * WM + i * 16 + (lane & 15)) * 64 + kk * 32 + (lane >> 4) * 8);
#pragma unroll
      for (int j = 0; j < NF; ++j)
        bf[j] = *(const f16x8*)(sB + (wn * WN + j * 16 + (lane & 15)) * 64 + kk * 32 + (lane >> 4) * 8);
#pragma unroll
      for (int i = 0; i < MF; ++i)
#pragma unroll
        for (int j = 0; j < NF; ++j)
          acc[i][j] = __builtin_amdgcn_mfma_f32_16x16x32_f16(af[i], bf[j], acc[i][j], 0, 0, 0);
    }
    __syncthreads();
  }

  const int r0 = bm * BM + wm * WM;
  const int c0 = bn * BN + wn * WN;

  if constexpr (EPI == EPI_POSE) {
#pragma unroll
    for (int i = 0; i < MF; ++i)
#pragma unroll
      for (int j = 0; j < NF; ++j)
#pragma unroll
        for (int r = 0; r < 4; ++r) {
          const int row = r0 + i * 16 + ((lane >> 4) << 2) + r;
          const int col = c0 + j * 16 + (lane & 15);
          float v = acc[i][j][r] + p.bias[col];
          p.inp[(size_t)row * KC + H + col] = (f16)v;
          if (col < DIM)
            p.outp[(size_t)row * (T * DIM) + (size_t)p.t * DIM + col] = v;
        }
  } else {
#pragma unroll
    for (int i = 0; i < MF; ++i)
#pragma unroll
      for (int j = 0; j < NF; ++j)
#pragma unroll
        for (int r = 0; r < 4; ++r) {
          const int row = r0 + i * 16 + ((lane >> 4) << 2) + r;
          const int col = c0 + j * 16 + (lane & 15);
          float v = acc[i][j][r] + p.bias[col];
          if constexpr (EPI == EPI_RELU_F16) v = fmaxf(v, 0.f);
          if constexpr (EPI == EPI_GATESX)
            p.O[(size_t)row * G4 + ((size_t)(col & 1023) << 2) + (col >> 10)] = (f16)v;
          else
            p.O[(size_t)row * p.ldO + col] = (f16)v;
        }
  }
}

// ---------- S1: 256x256 8-phase gates GEMM + fused LSTM cell ----------
// vmcnt ledger (issue order per tile: A0,A2 @p0 | B0..B3 @p1 | A1,A3 @p2 | p3 none):
//   p0 needs A-low + all B of cur tile; outstanding = {A1,A3} prev-issued -> vmcnt(2)
//   p2 needs A-high; issued since = A-low(2) + B(4) = 6 -> vmcnt(6)
// XCD-pinned grid: 1-D 256 blocks; xcd=id&7 owns bn in {2*xcd, 2*xcd+1} x all bm
// -> wcat/gx slices L2-resident per XCD; bm-paired order for A-slice L2 reuse.

#define WAITV(N) asm volatile("s_waitcnt vmcnt(" #N ")" ::: "memory")
#define BARRIER()                          \
  {                                        \
    asm volatile("" ::: "memory");         \
    __builtin_amdgcn_s_barrier();          \
    asm volatile("" ::: "memory");         \
  }

#define RD_A(SLOT, MH, DST)                                                         \
  _Pragma("unroll") for (int fi = 0; fi < 4; ++fi)                                  \
  _Pragma("unroll") for (int kk = 0; kk < 2; ++kk)                                  \
      DST[fi * 2 + kk] = *(const f16x8*)(lds + (SLOT) * 32768 +                     \
          (mb + ((MH) * 4 + fi) * 16) * 64 + ((kk * 32 + ck0) ^ swf));

#define RD_B(SLOT, NH, DST)                                                         \
  _Pragma("unroll") for (int fj = 0; fj < 2; ++fj)                                  \
  _Pragma("unroll") for (int kk = 0; kk < 2; ++kk)                                  \
      DST[fj * 2 + kk] = *(const f16x8*)(lds + (SLOT) * 32768 + 16384 +             \
          (nb + ((NH) * 2 + fj) * 16) * 64 + ((kk * 32 + ck0) ^ swf));

#define MFMA8(MH, NH, A_, B_)                                                       \
  __builtin_amdgcn_s_setprio(1);                                                    \
  _Pragma("unroll") for (int kk = 0; kk < 2; ++kk)                                  \
  _Pragma("unroll") for (int fi = 0; fi < 4; ++fi)                                  \
  _Pragma("unroll") for (int fj = 0; fj < 2; ++fj)                                  \
      acc[(MH) * 4 + fi][(NH) * 2 + fj] = __builtin_amdgcn_mfma_f32_16x16x32_f16(   \
          A_[fi * 2 + kk], B_[fj * 2 + kk], acc[(MH) * 4 + fi][(NH) * 2 + fj], 0, 0, 0); \
  __builtin_amdgcn_s_setprio(0);

#define ST_A(D, IT, TILE) \
  gload16(ldsA + (D) * 32768 + (IT) * 4096, gA + (size_t)(64 * (IT)) * KC + (TILE) * 64)
#define ST_B(D, IT, TILE) \
  gload16(ldsB + (D) * 32768 + (IT) * 4096, gB + (size_t)(16 * (IT)) * KC + (TILE) * 64)

__global__ __launch_bounds__(512, 2)
void lstm_gates_8ph(const f16* __restrict__ A, const f16* __restrict__ Bw,
                    const f16* __restrict__ gx, float* __restrict__ c32,
                    f16* __restrict__ inp) {
  __shared__ __align__(16) f16 lds[65536];  // 128 KiB: [slot][A 16384 | B 16384]

  const int tid = threadIdx.x, lane = tid & 63;
  const int wv = tid >> 6, wm = wv >> 2, wn = wv & 3;
  // XCD-pinned bijective remap (grid = 256, 1-D)
  const int id = blockIdx.x;
  const int xcd = id & 7, idx = id >> 3;
  const int bn = xcd * 2 + (idx & 1);
  const int bm = idx >> 1;

  const int rr = tid >> 3;             // 0..63
  const int c0 = (tid & 7) * 8;
  const int swst = (rr & 7) << 3;      // row-XOR swizzle (f16 units)
  const int cs = c0 ^ swst;            // pre-swizzled source col
  const f16* gA = A + (size_t)(bm * 256 + rr) * KC + cs;
  const int grow0 = (tid >> 7) * 1024 + bn * 64 + ((tid >> 3) & 15);  // gate-major B row
  const f16* gB = Bw + (size_t)grow0 * KC + cs;
  f16* ldsA = lds + tid * 8;
  f16* ldsB = lds + 16384 + tid * 8;

  const int ck0 = (lane >> 4) * 8;
  const int swf = (lane & 7) << 3;
  const int mb = wm * 128 + (lane & 15);
  const int nb = wn * 64 + (lane & 15);

  f32x4 acc[8][4] = {};
  f16x8 afr[8], bfr0[4], bfr1[4];

  // prologue: stage tile 0 (slot 0) in ledger order A0,A2, B0..B3, A1,A3
  ST_A(0, 0, 0); ST_A(0, 2, 0);
  ST_B(0, 0, 0); ST_B(0, 1, 0);
  ST_B(0, 2, 0); ST_B(0, 3, 0);
  ST_A(0, 1, 0); ST_A(0, 3, 0);

  for (int kt = 0; kt < 16; ++kt) {
    const int s = kt & 1, d = s ^ 1, nt = kt + 1;
    // p0: quadrant (0,0)
    WAITV(2); BARRIER();
    RD_A(s, 0, afr); RD_B(s, 0, bfr0);
    ST_A(d, 0, nt); ST_A(d, 2, nt);
    MFMA8(0, 0, afr, bfr0);
    // p1: quadrant (0,1) — stage ALL B chunks (3-phase lead)
    BARRIER();
    RD_B(s, 1, bfr1);
    ST_B(d, 0, nt); ST_B(d, 1, nt);
    ST_B(d, 2, nt); ST_B(d, 3, nt);
    MFMA8(0, 1, afr, bfr1);
    // p2: quadrant (1,1) — stage A-high (4-phase lead)
    WAITV(6); BARRIER();
    RD_A(s, 1, afr);
    ST_A(d, 1, nt); ST_A(d, 3, nt);
    MFMA8(1, 1, afr, bfr1);
    // p3: quadrant (1,0) — register-only
    BARRIER();
    MFMA8(1, 0, afr, bfr0);
  }

  // tail tile kt=16 (slot 0), drains 2 -> 0
  WAITV(2); BARRIER();
  RD_A(0, 0, afr); RD_B(0, 0, bfr0);
  MFMA8(0, 0, afr, bfr0);
  RD_B(0, 1, bfr1);
  MFMA8(0, 1, afr, bfr1);
  WAITV(0); BARRIER();
  RD_A(0, 1, afr);
  MFMA8(1, 1, afr, bfr1);
  MFMA8(1, 0, afr, bfr0);

  // fused LSTM cell epilogue
  const int jg = (bn * 4 + wn) * 16 + (lane & 15);
  const int r0 = bm * 256 + wm * 128;
#pragma unroll
  for (int i = 0; i < 8; ++i) {
#pragma unroll
    for (int r = 0; r < 4; ++r) {
      const int row = r0 + i * 16 + ((lane >> 4) << 2) + r;
      f16x4 g4v = *(const f16x4*)(gx + (size_t)row * G4 + jg * 4);
      float ig = acc[i][0][r] + (float)g4v[0];
      float fg = acc[i][1][r] + (float)g4v[1];
      float gg = acc[i][2][r] + (float)g4v[2];
      float og = acc[i][3][r] + (float)g4v[3];
      float c = c32[(size_t)row * H + jg];
      c = sigf(fg) * c + sigf(ig) * tanh_fast(gg);
      float h = sigf(og) * tanh_fast(c);
      c32[(size_t)row * H + jg] = c;
      inp[(size_t)row * KC + jg] = (f16)h;
    }
  }
}

// ---------- fused S2+S3: t1 = relu(h@W1^T + b1); pose = t1@W2^T + b2 ----------
// BM=32 rows/block, grid 128, 512 thr (8 waves, wave-tile 32x64 over N=512).
// Main loop: 2-phase counted-vmcnt dbuf (stage next tile, vmcnt(9/8), barrier, MFMA).
// t1 kept in LDS (f16 cvt = identical rounding to old t16 store); pose MFMA in-LDS
// with identical K-order -> bit-identical to the old S2+S3 pair.
// LDS: 2 x (sA 4KB | sB 64KB) = 136 KB; t1 [32][512] aliases buf0; W2 aliases buf1.
__global__ __launch_bounds__(512, 1)
void fused_s23(const f16* __restrict__ inpr, const f16* __restrict__ W1,
               const float* __restrict__ b1, const f16* __restrict__ W2p,
               const float* __restrict__ b2pp, f16* __restrict__ inpw,
               float* __restrict__ outp, int t) {
  __shared__ __align__(16) f16 lds[69632];  // 2*34816 f16 = 136 KiB

  const int tid = threadIdx.x, lane = tid & 63, wv = tid >> 6;
  const int bm = blockIdx.x;

  const int rrA = (tid & 255) >> 3;    // 0..31 (waves 0..3)
  const int rrB = tid >> 3;            // 0..63
  const int c0 = (tid & 7) * 8;
  const f16* gA = inpr + (size_t)(bm * 32 + rrA) * KC + (c0 ^ ((rrA & 7) << 3));
  const f16* gB = W1 + (size_t)rrB * H + (c0 ^ ((rrB & 7) << 3));

  const int ck0 = (lane >> 4) * 8;
  const int swf = (lane & 7) << 3;

  auto STAGE = [&](int d, int k0) {
    f16* Lb = lds + d * 34816;
    if (wv < 4) gload16(Lb + (tid & 255) * 8, gA + k0);          // sA: 32x64
#pragma unroll
    for (int it = 0; it < 8; ++it)                               // sB: 512x64
      gload16(Lb + 2048 + it * 4096 + tid * 8, gB + (size_t)(it * 64) * H + k0);
  };

  f32x4 acc[2][4] = {};

  STAGE(0, 0);
  for (int kt = 0; kt < 16; ++kt) {
    const int s = kt & 1;
    if (kt < 15) {
      STAGE(s ^ 1, (kt + 1) * 64);
      if (wv < 4) { WAITV(9); } else { WAITV(8); }   // wave-uniform branch
    } else {
      WAITV(0);
    }
    BARRIER();
    const f16* Ls = lds + s * 34816;
#pragma unroll
    for (int kk = 0; kk < 2; ++kk) {
      f16x8 af[2], bf[4];
#pragma unroll
      for (int i = 0; i < 2; ++i)
        af[i] = *(const f16x8*)(Ls + (i * 16 + (lane & 15)) * 64 + ((kk * 32 + ck0) ^ swf));
#pragma unroll
      for (int j = 0; j < 4; ++j)
        bf[j] = *(const f16x8*)(Ls + 2048 + (wv * 64 + j * 16 + (lane & 15)) * 64 + ((kk * 32 + ck0) ^ swf));
#pragma unroll
      for (int i = 0; i < 2; ++i)
#pragma unroll
        for (int j = 0; j < 4; ++j)
          acc[i][j] = __builtin_amdgcn_mfma_f32_16x16x32_f16(af[i], bf[j], acc[i][j], 0, 0, 0);
    }
    BARRIER();
  }

  // t1 = relu(acc + b1) -> LDS [32][512] swizzled (f16, same rounding as old t16)
  float b1v[4];
#pragma unroll
  for (int j = 0; j < 4; ++j) b1v[j] = b1[wv * 64 + j * 16 + (lane & 15)];
#pragma unroll
  for (int i = 0; i < 2; ++i)
#pragma unroll
    for (int j = 0; j < 4; ++j)
#pragma unroll
      for (int r = 0; r < 4; ++r) {
        const int row = i * 16 + ((lane >> 4) << 2) + r;
        const int col = wv * 64 + j * 16 + (lane & 15);
        float v = fmaxf(acc[i][j][r] + b1v[j], 0.f);
        lds[row * 512 + (col ^ ((row & 7) << 3))] = (f16)v;
      }
  // stage W2 [64][512] -> buf1 region (pre-swizzled source)
#pragma unroll
  for (int it = 0; it < 8; ++it) {
    const int q = it * 512 + tid, rw = q >> 6, cc = q & 63;
    gload16(lds + 34816 + q * 8, W2p + (size_t)rw * 512 + ((cc * 8) ^ ((rw & 7) << 3)));
  }
  __syncthreads();  // drains ds_writes (t1) + gload (W2)

  // pose = t1 @ W2^T + b2: wave wv -> (wm2 = wv&1) x (wn2 = wv>>1), K = 512
  const int wm2 = wv & 1, wn2 = wv >> 1;
  const int ra = (wm2 * 16 + (lane & 15)) * 512;
  const int rb = 34816 + (wn2 * 16 + (lane & 15)) * 512;
  f32x4 pacc = {};
#pragma unroll
  for (int ks = 0; ks < 16; ++ks) {
    f16x8 a = *(const f16x8*)(lds + ra + ((ks * 32 + ck0) ^ swf));
    f16x8 b = *(const f16x8*)(lds + rb + ((ks * 32 + ck0) ^ swf));
    pacc = __builtin_amdgcn_mfma_f32_16x16x32_f16(a, b, pacc, 0, 0, 0);
  }
  const int pcol = wn2 * 16 + (lane & 15);
  const float pb = b2pp[pcol];
#pragma unroll
  for (int r = 0; r < 4; ++r) {
    const int row = bm * 32 + wm2 * 16 + ((lane >> 4) << 2) + r;
    float v = pacc[r] + pb;
    inpw[(size_t)row * KC + H + pcol] = (f16)v;
    if (pcol < DIM)
      outp[(size_t)row * (T * DIM) + (size_t)t * DIM + pcol] = v;
  }
}

// ---------------- prologue helper kernels ----------------
__global__ void k_cvt(const float* s, f16* d, int n) {
  for (int i = blockIdx.x * blockDim.x + threadIdx.x; i < n; i += gridDim.x * blockDim.x)
    d[i] = (f16)s[i];
}
__global__ void k_pad_rows(const float* s, f16* d, int rows, int n) {
  for (int i = blockIdx.x * blockDim.x + threadIdx.x; i < n; i += gridDim.x * blockDim.x) {
    int r = i >> 9;
    d[i] = (r < rows) ? (f16)s[i] : (f16)0.f;
  }
}
__global__ void k_pack_wihx(const float* W, f16* d) {
  for (int i = blockIdx.x * blockDim.x + threadIdx.x; i < G4 * DZ; i += gridDim.x * blockDim.x) {
    int n = i >> 9, k = i & 511;
    d[i] = (f16)W[n * 575 + k];
  }
}
__global__ void k_pack_wcat(const float* Wih, const float* Whh, f16* d) {
  for (int i = blockIdx.x * blockDim.x + threadIdx.x; i < G4 * KC; i += gridDim.x * blockDim.x) {
    int n = i / KC, k = i - n * KC;
    float v = (k < H) ? Whh[n * H + k] : ((k < H + DIM) ? Wih[n * 575 + DZ + (k - H)] : 0.f);
    d[i] = (f16)v;
  }
}
__global__ void k_bias(const float* bih, const float* bhh, float* bsum,
                       const float* bp2, float* bp2p, const float* b2, float* b2p) {
  int i = blockIdx.x * blockDim.x + threadIdx.x;
  if (i < G4) bsum[i] = bih[i] + bhh[i];
  if (i < 64) {
    bp2p[i] = (i < DIM) ? bp2[i] : 0.f;
    b2p[i]  = (i < DIM) ? b2[i]  : 0.f;
  }
}
__global__ void k_init(float* c32, f16* inp) {
  for (int i = blockIdx.x * blockDim.x + threadIdx.x; i < Bsz * H; i += gridDim.x * blockDim.x) {
    c32[i] = 0.f;
    inp[(size_t)(i >> 10) * KC + (i & 1023)] = (f16)0.f;
  }
}

extern "C" void kernel_launch(void* const* d_in, const int* in_sizes, int n_in,
                              void* d_out, int out_size, void* d_ws, size_t ws_size,
                              hipStream_t stream) {
  const float* x_in = (const float*)d_in[0];
  const float* Wlin = (const float*)d_in[1];
  const float* blin = (const float*)d_in[2];
  const float* Wp1  = (const float*)d_in[3];
  const float* bp1  = (const float*)d_in[4];
  const float* Wp2  = (const float*)d_in[5];
  const float* bp2  = (const float*)d_in[6];
  const float* Wih  = (const float*)d_in[7];
  const float* bih  = (const float*)d_in[8];
  const float* Whh  = (const float*)d_in[9];
  const float* bhh  = (const float*)d_in[10];
  const float* W1   = (const float*)d_in[11];
  const float* b1   = (const float*)d_in[12];
  const float* W2   = (const float*)d_in[13];
  const float* b2   = (const float*)d_in[14];
  float* out = (float*)d_out;

  char* w = (char*)d_ws;
  auto alloc = [&](size_t bytes) { char* r = w; w += (bytes + 255) & ~(size_t)255; return r; };
  f16*   inpA   = (f16*)alloc((size_t)Bsz * KC * 2);
  f16*   inpB   = (f16*)alloc((size_t)Bsz * KC * 2);
  float* c32    = (float*)alloc((size_t)Bsz * H * 4);
  f16*   gx16   = (f16*)alloc((size_t)Bsz * G4 * 2);
  f16*   wcat   = (f16*)alloc((size_t)G4 * KC * 2);
  f16*   wihx   = (f16*)alloc((size_t)G4 * DZ * 2);
  f16*   wlin16 = (f16*)alloc((size_t)DZ * DZ * 2);
  f16*   wp1_16 = (f16*)alloc((size_t)DZ * DZ * 2);
  f16*   wp2p   = (f16*)alloc((size_t)64 * DZ * 2);
  f16*   w1_16  = (f16*)alloc((size_t)DZ * H * 2);
  f16*   w2p    = (f16*)alloc((size_t)64 * DZ * 2);
  f16*   xin16  = (f16*)alloc((size_t)Bsz * DZ * 2);
  f16*   x16    = (f16*)alloc((size_t)Bsz * DZ * 2);
  f16*   t16    = (f16*)alloc((size_t)Bsz * DZ * 2);
  float* bsum   = (float*)alloc((size_t)G4 * 4);
  float* bp2p_  = (float*)alloc(64 * 4);
  float* b2p    = (float*)alloc(64 * 4);

  dim3 blk(256);
  auto g1 = [](int n) { int b = (n + 255) / 256; return dim3(b > 2048 ? 2048 : b); };

  k_cvt<<<g1(Bsz * DZ), blk, 0, stream>>>(x_in, xin16, Bsz * DZ);
  k_cvt<<<g1(DZ * DZ), blk, 0, stream>>>(Wlin, wlin16, DZ * DZ);
  k_cvt<<<g1(DZ * DZ), blk, 0, stream>>>(Wp1, wp1_16, DZ * DZ);
  k_cvt<<<g1(DZ * H), blk, 0, stream>>>(W1, w1_16, DZ * H);
  k_pad_rows<<<g1(64 * DZ), blk, 0, stream>>>(Wp2, wp2p, DIM, 64 * DZ);
  k_pad_rows<<<g1(64 * DZ), blk, 0, stream>>>(W2, w2p, DIM, 64 * DZ);
  k_pack_wihx<<<g1(G4 * DZ), blk, 0, stream>>>(Wih, wihx);
  k_pack_wcat<<<g1(G4 * KC), blk, 0, stream>>>(Wih, Whh, wcat);
  k_bias<<<16, blk, 0, stream>>>(bih, bhh, bsum, bp2, bp2p_, b2, b2p);
  k_init<<<g1(Bsz * H), blk, 0, stream>>>(c32, inpA);

  // G1: x = relu(x_in @ W_lin^T + b_lin)
  GArgs a{};
  a.A = xin16; a.ldA = DZ; a.Bm = wlin16; a.ldB = DZ; a.K = DZ;
  a.bias = blin; a.O = x16; a.ldO = DZ;
  gemm_k<64, 128, 32, 64, EPI_RELU_F16><<<dim3(Bsz / 64, 4), 256, 0, stream>>>(a);
  // G2: t = relu(x @ W_p1^T + b_p1)
  a.A = x16; a.Bm = wp1_16; a.bias = bp1; a.O = t16;
  gemm_k<64, 128, 32, 64, EPI_RELU_F16><<<dim3(Bsz / 64, 4), 256, 0, stream>>>(a);
  // G3: pose0 = t @ W_p2^T + b_p2 -> inpA pose region
  GArgs a3{};
  a3.A = t16; a3.ldA = DZ; a3.Bm = wp2p; a3.ldB = DZ; a3.K = DZ;
  a3.bias = bp2p_; a3.O = inpA + H; a3.ldO = KC;
  gemm_k<64, 64, 32, 32, EPI_F16><<<dim3(Bsz / 64, 1), 256, 0, stream>>>(a3);
  // G4: gates_x = x @ W_ihx^T + (b_ih + b_hh), stored f16 permuted [row][j*4+gate]
  GArgs a4{};
  a4.A = x16; a4.ldA = DZ; a4.Bm = wihx; a4.ldB = DZ; a4.K = DZ;
  a4.bias = bsum; a4.O = gx16;
  gemm_k<128, 128, 32, 128, EPI_GATESX><<<dim3(Bsz / 128, G4 / 128), 256, 0, stream>>>(a4);

  for (int t = 0; t < T; ++t) {
    f16* cur = (t & 1) ? inpB : inpA;
    f16* nxt = (t & 1) ? inpA : inpB;
    // S1: 8-phase gates GEMM + fused LSTM cell (XCD-pinned 1-D grid)
    lstm_gates_8ph<<<dim3(256), 512, 0, stream>>>(cur, wcat, gx16, c32, nxt);
    // S2+S3 fused: t1 in LDS, pose -> out[:, t, :] and nxt pose region
    fused_s23<<<dim3(128), 512, 0, stream>>>(nxt, w1_16, b1, w2p, b2p, nxt, out, t);
  }
}